// Round 5
// baseline (1645.636 us; speedup 1.0000x reference)
//
#include <hip/hip_runtime.h>

// MsgPassingNN: 3 rounds of edge-MLP + segment_sum + node-MLP.
// N=100000 nodes (D=16), E=3200000 edges.
// fe: 32 -> 9 (relu) -> 9 (relu) -> 9 ; fx: 25 -> 9 (relu) -> 9 (relu) -> 16
//
// R4 structure:
//   Build: bucket sort by dst>>7 (782 buckets) with LDS-STAGED scatter so
//   global writes are contiguous runs (R3's random 4B stores caused partial
//   32B sectors across XCD L2s -> ~100us). Output sed2 = u64 (dst<<32|src),
//   grouped by bucket.
//   Round: one block per bucket (512 thr), batch-4 edges per weight fetch.
//   Layer1 = relu(base1[dst] + p[src]) with base1/p precomputed per node in
//   GLOBAL 12-padded rows (VMEM pipe, L1-hot) by the node kernel epilogue.
//   Weight rows padded to 12 floats -> ds_read_b128. Message accumulation in
//   LDS lacc with stride 13 (odd -> conflict-free banks; R3's stride 12 hit
//   8-way conflicts = 1.23M counted). Drain = plain stores (bucket wholly
//   owned by one block -> zero global atomics, no m zero-init).

constexpr int NN = 100000;
constexpr int NE = 3200000;
constexpr int NB = 782;               // buckets of 128 nodes
constexpr int NBLD = (NE + 4095) / 4096;   // 782 build blocks, 4096 edges each

// ---------------- build ----------------

__global__ __launch_bounds__(256) void h1_k(const int* __restrict__ dst,
                                            int* __restrict__ gcnt,
                                            int* __restrict__ bbase)
{
    __shared__ int lcnt[NB];
    const int t = threadIdx.x;
    for (int i = t; i < NB; i += 256) lcnt[i] = 0;
    __syncthreads();
    const int e0 = blockIdx.x * 4096;
    const int e1 = min(e0 + 4096, NE);
    for (int e = e0 + t; e < e1; e += 256) atomicAdd(&lcnt[dst[e] >> 7], 1);
    __syncthreads();
    for (int b = t; b < NB; b += 256) {
        int c = lcnt[b];
        bbase[blockIdx.x * NB + b] = c ? atomicAdd(&gcnt[b], c) : 0;
    }
}

__global__ __launch_bounds__(1024) void scan_k(const int* __restrict__ gcnt,
                                               int* __restrict__ bstart)
{
    __shared__ int s[1024];
    const int t = threadIdx.x;
    int v = (t < NB) ? gcnt[t] : 0;
    s[t] = v;
    __syncthreads();
    for (int off = 1; off < 1024; off <<= 1) {
        int a = (t >= off) ? s[t - off] : 0;
        __syncthreads();
        s[t] += a;
        __syncthreads();
    }
    if (t < NB) bstart[t + 1] = s[t];
    if (t == 0) bstart[0] = 0;
}

__global__ __launch_bounds__(256) void s1_k(const int* __restrict__ src,
                                            const int* __restrict__ dst,
                                            const int* __restrict__ bstart,
                                            const int* __restrict__ bbase,
                                            unsigned long long* __restrict__ sed2)
{
    __shared__ int lcnt[NB];
    __shared__ int sA[NB], sB[NB];
    __shared__ unsigned long long lbuf[4096];
    const int t = threadIdx.x;
    for (int i = t; i < NB; i += 256) lcnt[i] = 0;
    __syncthreads();
    const int e0 = blockIdx.x * 4096;
    const int n = min(4096, NE - e0);

    int dd[16], ss[16], rr[16];
    #pragma unroll
    for (int k = 0; k < 16; ++k) {
        int e = e0 + k * 256 + t;
        if (e < e0 + n) {
            dd[k] = dst[e]; ss[k] = src[e];
            rr[k] = atomicAdd(&lcnt[dd[k] >> 7], 1);
        }
    }
    __syncthreads();
    // inclusive scan of lcnt (Hillis-Steele, ping-pong)
    for (int i = t; i < NB; i += 256) sA[i] = lcnt[i];
    __syncthreads();
    int* pin = sA; int* pout = sB;
    for (int off = 1; off < NB; off <<= 1) {
        for (int i = t; i < NB; i += 256)
            pout[i] = pin[i] + ((i >= off) ? pin[i - off] : 0);
        __syncthreads();
        int* tmp = pin; pin = pout; pout = tmp;
    }
    // pin = inclusive scan; exclusive = pin[b] - lcnt[b]
    #pragma unroll
    for (int k = 0; k < 16; ++k) {
        int e = e0 + k * 256 + t;
        if (e < e0 + n) {
            int b = dd[k] >> 7;
            int pos = pin[b] - lcnt[b] + rr[k];
            lbuf[pos] = ((unsigned long long)(unsigned)dd[k] << 32) | (unsigned)ss[k];
        }
    }
    __syncthreads();
    for (int i = t; i < n; i += 256) {
        unsigned long long pl = lbuf[i];
        int d = (int)(pl >> 32);
        int b = d >> 7;
        int pos = bstart[b] + bbase[blockIdx.x * NB + b] + (i - (pin[b] - lcnt[b]));
        sed2[pos] = pl;
    }
}

// ---------------- init: p, base1 from X0 ----------------

__global__ __launch_bounds__(512) void init4_k(const float* __restrict__ X,
                                               const float* __restrict__ feW1,
                                               const float* __restrict__ feb1,
                                               float* __restrict__ p,
                                               float* __restrict__ base1)
{
    __shared__ float sWd[144], sWs[144], sb1[9];
    const int t = threadIdx.x;
    if (t < 144) { sWd[t] = feW1[t]; sWs[t] = feW1[144 + t]; }
    if (t < 9) sb1[t] = feb1[t];
    __syncthreads();
    const int nidx = blockIdx.x * 512 + t;
    if (nidx >= NN) return;
    float x[16];
    const float4* q = reinterpret_cast<const float4*>(X + (size_t)nidx * 16);
    #pragma unroll
    for (int k = 0; k < 4; ++k) {
        float4 v = q[k];
        x[4*k] = v.x; x[4*k+1] = v.y; x[4*k+2] = v.z; x[4*k+3] = v.w;
    }
    float a[9], b[9];
    #pragma unroll
    for (int j = 0; j < 9; ++j) { a[j] = 0.f; b[j] = sb1[j]; }
    #pragma unroll
    for (int i = 0; i < 16; ++i) {
        const float xi = x[i];
        #pragma unroll
        for (int j = 0; j < 9; ++j) {
            a[j] = fmaf(xi, sWs[i * 9 + j], a[j]);
            b[j] = fmaf(xi, sWd[i * 9 + j], b[j]);
        }
    }
    float* pp = p + (size_t)nidx * 12;
    float* bp = base1 + (size_t)nidx * 12;
    #pragma unroll
    for (int j = 0; j < 9; ++j) { pp[j] = a[j]; bp[j] = b[j]; }
}

// ---------------- edge round: one block per bucket, batch-4 ----------------

__global__ __launch_bounds__(512) void round4_k(
    const unsigned long long* __restrict__ sed2,
    const int* __restrict__ bstart,
    const float* __restrict__ p,
    const float* __restrict__ base1,
    const float* __restrict__ feW2, const float* __restrict__ feb2,
    const float* __restrict__ feW3, const float* __restrict__ feb3,
    float* __restrict__ m)
{
    __shared__ __align__(16) float sW2[9 * 12], sW3[9 * 12];
    __shared__ float sb2s[9], sb3s[9];
    __shared__ float lacc[128 * 13];   // stride 13: odd -> all 32 banks
    const int t = threadIdx.x;
    if (t < 108) {
        int r = t / 12, c = t % 12;
        sW2[t] = (c < 9) ? feW2[r * 9 + c] : 0.f;
        sW3[t] = (c < 9) ? feW3[r * 9 + c] : 0.f;
    }
    if (t >= 128 && t < 137) sb2s[t - 128] = feb2[t - 128];
    if (t >= 160 && t < 169) sb3s[t - 160] = feb3[t - 160];
    for (int i = t; i < 128 * 13; i += 512) lacc[i] = 0.f;
    __syncthreads();

    const int e0 = bstart[blockIdx.x];
    const int e1 = bstart[blockIdx.x + 1];

    for (int base = e0 + t * 4; base < e1; base += 512 * 4) {
        if (base + 4 <= e1) {
            // ---- fast path: 4 edges ----
            unsigned long long pk[4];
            const uint4* sp = reinterpret_cast<const uint4*>(sed2 + base);
            uint4 u0 = sp[0], u1 = sp[1];
            pk[0] = ((unsigned long long)u0.y << 32) | u0.x;
            pk[1] = ((unsigned long long)u0.w << 32) | u0.z;
            pk[2] = ((unsigned long long)u1.y << 32) | u1.x;
            pk[3] = ((unsigned long long)u1.w << 32) | u1.z;

            int ld[4];
            float A[4][9];
            #pragma unroll
            for (int k = 0; k < 4; ++k) {
                const int d = (int)(pk[k] >> 32);
                const int s = (int)(pk[k] & 0xffffffffu);
                ld[k] = d & 127;
                const float* pp = p + (size_t)s * 12;
                const float* bb = base1 + (size_t)d * 12;
                float4 pa = *(const float4*)pp;
                float4 pb = *(const float4*)(pp + 4);
                float  pc = pp[8];
                float4 ba = *(const float4*)bb;
                float4 bc4 = *(const float4*)(bb + 4);
                float  bc = bb[8];
                A[k][0] = fmaxf(pa.x + ba.x, 0.f);
                A[k][1] = fmaxf(pa.y + ba.y, 0.f);
                A[k][2] = fmaxf(pa.z + ba.z, 0.f);
                A[k][3] = fmaxf(pa.w + ba.w, 0.f);
                A[k][4] = fmaxf(pb.x + bc4.x, 0.f);
                A[k][5] = fmaxf(pb.y + bc4.y, 0.f);
                A[k][6] = fmaxf(pb.z + bc4.z, 0.f);
                A[k][7] = fmaxf(pb.w + bc4.w, 0.f);
                A[k][8] = fmaxf(pc + bc, 0.f);
            }

            float H[4][9];
            #pragma unroll
            for (int k = 0; k < 4; ++k)
                #pragma unroll
                for (int j = 0; j < 9; ++j) H[k][j] = sb2s[j];
            #pragma unroll
            for (int i = 0; i < 9; ++i) {
                float4 wa = *(const float4*)(sW2 + i * 12);
                float4 wb = *(const float4*)(sW2 + i * 12 + 4);
                float  wc = sW2[i * 12 + 8];
                #pragma unroll
                for (int k = 0; k < 4; ++k) {
                    const float x = A[k][i];
                    H[k][0] = fmaf(x, wa.x, H[k][0]);
                    H[k][1] = fmaf(x, wa.y, H[k][1]);
                    H[k][2] = fmaf(x, wa.z, H[k][2]);
                    H[k][3] = fmaf(x, wa.w, H[k][3]);
                    H[k][4] = fmaf(x, wb.x, H[k][4]);
                    H[k][5] = fmaf(x, wb.y, H[k][5]);
                    H[k][6] = fmaf(x, wb.z, H[k][6]);
                    H[k][7] = fmaf(x, wb.w, H[k][7]);
                    H[k][8] = fmaf(x, wc,   H[k][8]);
                }
            }
            #pragma unroll
            for (int k = 0; k < 4; ++k)
                #pragma unroll
                for (int j = 0; j < 9; ++j) H[k][j] = fmaxf(H[k][j], 0.f);

            float O[4][9];
            #pragma unroll
            for (int k = 0; k < 4; ++k)
                #pragma unroll
                for (int j = 0; j < 9; ++j) O[k][j] = sb3s[j];
            #pragma unroll
            for (int i = 0; i < 9; ++i) {
                float4 wa = *(const float4*)(sW3 + i * 12);
                float4 wb = *(const float4*)(sW3 + i * 12 + 4);
                float  wc = sW3[i * 12 + 8];
                #pragma unroll
                for (int k = 0; k < 4; ++k) {
                    const float x = H[k][i];
                    O[k][0] = fmaf(x, wa.x, O[k][0]);
                    O[k][1] = fmaf(x, wa.y, O[k][1]);
                    O[k][2] = fmaf(x, wa.z, O[k][2]);
                    O[k][3] = fmaf(x, wa.w, O[k][3]);
                    O[k][4] = fmaf(x, wb.x, O[k][4]);
                    O[k][5] = fmaf(x, wb.y, O[k][5]);
                    O[k][6] = fmaf(x, wb.z, O[k][6]);
                    O[k][7] = fmaf(x, wb.w, O[k][7]);
                    O[k][8] = fmaf(x, wc,   O[k][8]);
                }
            }
            #pragma unroll
            for (int k = 0; k < 4; ++k) {
                float* lp = lacc + ld[k] * 13;
                #pragma unroll
                for (int j = 0; j < 9; ++j) atomicAdd(lp + j, O[k][j]);
            }
        } else {
            // ---- tail: < 4 edges, scalar per edge ----
            for (int e = base; e < e1; ++e) {
                const unsigned long long pkv = sed2[e];
                const int d = (int)(pkv >> 32);
                const int s = (int)(pkv & 0xffffffffu);
                const int l = d & 127;
                const float* pp = p + (size_t)s * 12;
                const float* bb = base1 + (size_t)d * 12;
                float a[9];
                #pragma unroll
                for (int j = 0; j < 9; ++j) a[j] = fmaxf(pp[j] + bb[j], 0.f);
                float h[9];
                #pragma unroll
                for (int j = 0; j < 9; ++j) h[j] = sb2s[j];
                #pragma unroll
                for (int i = 0; i < 9; ++i) {
                    const float x = a[i];
                    #pragma unroll
                    for (int j = 0; j < 9; ++j) h[j] = fmaf(x, sW2[i * 12 + j], h[j]);
                }
                #pragma unroll
                for (int j = 0; j < 9; ++j) h[j] = fmaxf(h[j], 0.f);
                float o[9];
                #pragma unroll
                for (int j = 0; j < 9; ++j) o[j] = sb3s[j];
                #pragma unroll
                for (int i = 0; i < 9; ++i) {
                    const float x = h[i];
                    #pragma unroll
                    for (int j = 0; j < 9; ++j) o[j] = fmaf(x, sW3[i * 12 + j], o[j]);
                }
                float* lp = lacc + l * 13;
                #pragma unroll
                for (int j = 0; j < 9; ++j) atomicAdd(lp + j, o[j]);
            }
        }
    }
    __syncthreads();

    // drain: plain stores (this block owns the whole bucket)
    const int node0 = blockIdx.x << 7;
    const int nn = min(128, NN - node0);
    for (int r = t; r < nn; r += 512) {
        const float* lp = lacc + r * 13;
        float v0 = lp[0], v1 = lp[1], v2 = lp[2], v3 = lp[3];
        float v4 = lp[4], v5 = lp[5], v6 = lp[6], v7 = lp[7], v8 = lp[8];
        float* mp = m + (size_t)(node0 + r) * 12;
        float4 w0; w0.x = v0; w0.y = v1; w0.z = v2; w0.w = v3;
        float4 w1; w1.x = v4; w1.y = v5; w1.z = v6; w1.w = v7;
        ((float4*)mp)[0] = w0;
        ((float4*)mp)[1] = w1;
        mp[8] = v8;
    }
}

// ---------------- node round: fx MLP + next p/base1 ----------------

__global__ __launch_bounds__(512) void node4_k(
    const float* __restrict__ Xin, const float* __restrict__ m,
    const float* __restrict__ fxW1, const float* __restrict__ fxb1,
    const float* __restrict__ fxW2, const float* __restrict__ fxb2,
    const float* __restrict__ fxW3, const float* __restrict__ fxb3,
    const float* __restrict__ feW1, const float* __restrict__ feb1,
    float* __restrict__ Xout, float* __restrict__ p, float* __restrict__ base1)
{
    __shared__ float sU1[225], sU2[81], sU3[144];
    __shared__ float sWd[144], sWs[144];
    __shared__ float snb[34], sb1[9];
    const int t = threadIdx.x;
    if (t < 225) sU1[t] = fxW1[t];
    if (t < 81)  sU2[t] = fxW2[t];
    if (t < 144) { sU3[t] = fxW3[t]; sWd[t] = feW1[t]; sWs[t] = feW1[144 + t]; }
    if (t < 9) { snb[t] = fxb1[t]; snb[9 + t] = fxb2[t]; sb1[t] = feb1[t]; }
    if (t >= 32 && t < 48) snb[18 + (t - 32)] = fxb3[t - 32];
    __syncthreads();

    const int n = blockIdx.x * 512 + t;
    if (n >= NN) return;

    float xr[16];
    const float4* q = reinterpret_cast<const float4*>(Xin + (size_t)n * 16);
    #pragma unroll
    for (int k = 0; k < 4; ++k) {
        float4 v = q[k];
        xr[4*k] = v.x; xr[4*k+1] = v.y; xr[4*k+2] = v.z; xr[4*k+3] = v.w;
    }
    float mm[9];
    const float* mp = m + (size_t)n * 12;
    {
        float4 a = *(const float4*)mp;
        float4 b = *(const float4*)(mp + 4);
        mm[0] = a.x; mm[1] = a.y; mm[2] = a.z; mm[3] = a.w;
        mm[4] = b.x; mm[5] = b.y; mm[6] = b.z; mm[7] = b.w;
        mm[8] = mp[8];
    }

    float h1[9];
    #pragma unroll
    for (int j = 0; j < 9; ++j) h1[j] = snb[j];
    #pragma unroll
    for (int i = 0; i < 16; ++i) {
        const float xi = xr[i];
        #pragma unroll
        for (int j = 0; j < 9; ++j) h1[j] = fmaf(xi, sU1[i * 9 + j], h1[j]);
    }
    #pragma unroll
    for (int i = 0; i < 9; ++i) {
        const float xi = mm[i];
        #pragma unroll
        for (int j = 0; j < 9; ++j) h1[j] = fmaf(xi, sU1[(16 + i) * 9 + j], h1[j]);
    }
    #pragma unroll
    for (int j = 0; j < 9; ++j) h1[j] = fmaxf(h1[j], 0.f);

    float h2[9];
    #pragma unroll
    for (int j = 0; j < 9; ++j) h2[j] = snb[9 + j];
    #pragma unroll
    for (int i = 0; i < 9; ++i) {
        const float xi = h1[i];
        #pragma unroll
        for (int j = 0; j < 9; ++j) h2[j] = fmaf(xi, sU2[i * 9 + j], h2[j]);
    }
    #pragma unroll
    for (int j = 0; j < 9; ++j) h2[j] = fmaxf(h2[j], 0.f);

    float o[16];
    #pragma unroll
    for (int k = 0; k < 16; ++k) o[k] = snb[18 + k];
    #pragma unroll
    for (int j = 0; j < 9; ++j) {
        const float hj = h2[j];
        #pragma unroll
        for (int k = 0; k < 16; ++k) o[k] = fmaf(hj, sU3[j * 16 + k], o[k]);
    }

    float4* po = reinterpret_cast<float4*>(Xout + (size_t)n * 16);
    #pragma unroll
    for (int k = 0; k < 4; ++k) {
        float4 v;
        v.x = o[4*k]; v.y = o[4*k+1]; v.z = o[4*k+2]; v.w = o[4*k+3];
        po[k] = v;
    }

    // epilogue: p/base1 for next round
    float a[9], b[9];
    #pragma unroll
    for (int j = 0; j < 9; ++j) { a[j] = 0.f; b[j] = sb1[j]; }
    #pragma unroll
    for (int i = 0; i < 16; ++i) {
        const float xi = o[i];
        #pragma unroll
        for (int j = 0; j < 9; ++j) {
            a[j] = fmaf(xi, sWs[i * 9 + j], a[j]);
            b[j] = fmaf(xi, sWd[i * 9 + j], b[j]);
        }
    }
    float* pp = p + (size_t)n * 12;
    float* bp = base1 + (size_t)n * 12;
    #pragma unroll
    for (int j = 0; j < 9; ++j) { pp[j] = a[j]; bp[j] = b[j]; }
}

extern "C" void kernel_launch(void* const* d_in, const int* in_sizes, int n_in,
                              void* d_out, int out_size, void* d_ws, size_t ws_size,
                              hipStream_t stream)
{
    const float* X0   = (const float*)d_in[0];
    const int*   esrc = (const int*)d_in[1];
    const int*   edst = (const int*)d_in[2];
    const float* feW1 = (const float*)d_in[3];
    const float* feb1 = (const float*)d_in[4];
    const float* feW2 = (const float*)d_in[5];
    const float* feb2 = (const float*)d_in[6];
    const float* feW3 = (const float*)d_in[7];
    const float* feb3 = (const float*)d_in[8];
    const float* fxW1 = (const float*)d_in[9];
    const float* fxb1 = (const float*)d_in[10];
    const float* fxW2 = (const float*)d_in[11];
    const float* fxb2 = (const float*)d_in[12];
    const float* fxW3 = (const float*)d_in[13];
    const float* fxb3 = (const float*)d_in[14];
    float* out = (float*)d_out;

    // workspace (4B units), ~55 MB; sed2 first for 8/16B alignment
    unsigned long long* sed2 = (unsigned long long*)d_ws;       // NE u64
    float* Xa    = (float*)(sed2 + NE);                         // NN*16
    float* Xb    = Xa + (size_t)NN * 16;                        // NN*16
    float* p     = Xb + (size_t)NN * 16;                        // NN*12
    float* base1 = p + (size_t)NN * 12;                         // NN*12
    float* mb    = base1 + (size_t)NN * 12;                     // NN*12
    int* gcnt    = (int*)(mb + (size_t)NN * 12);                // NB (+pad)
    int* bstart  = gcnt + (NB + 2);                             // NB+1 (+pad)
    int* bbase   = bstart + (NB + 2);                           // NBLD*NB

    const dim3 gB(NBLD), tB(256);
    const dim3 gN((NN + 511) / 512), tN(512);
    const dim3 gR(NB), tR(512);

    // ---- build (once per launch) ----
    hipMemsetAsync(gcnt, 0, (size_t)NB * sizeof(int), stream);
    h1_k<<<gB, tB, 0, stream>>>(edst, gcnt, bbase);
    scan_k<<<1, 1024, 0, stream>>>(gcnt, bstart);
    s1_k<<<gB, tB, 0, stream>>>(esrc, edst, bstart, bbase, sed2);

    // ---- rounds: X0 -> Xa -> Xb -> out ----
    init4_k<<<gN, tN, 0, stream>>>(X0, feW1, feb1, p, base1);

    round4_k<<<gR, tR, 0, stream>>>(sed2, bstart, p, base1,
                                    feW2, feb2, feW3, feb3, mb);
    node4_k<<<gN, tN, 0, stream>>>(X0, mb, fxW1, fxb1, fxW2, fxb2, fxW3, fxb3,
                                   feW1, feb1, Xa, p, base1);

    round4_k<<<gR, tR, 0, stream>>>(sed2, bstart, p, base1,
                                    feW2, feb2, feW3, feb3, mb);
    node4_k<<<gN, tN, 0, stream>>>(Xa, mb, fxW1, fxb1, fxW2, fxb2, fxW3, fxb3,
                                   feW1, feb1, Xb, p, base1);

    round4_k<<<gR, tR, 0, stream>>>(sed2, bstart, p, base1,
                                    feW2, feb2, feW3, feb3, mb);
    node4_k<<<gN, tN, 0, stream>>>(Xb, mb, fxW1, fxb1, fxW2, fxb2, fxW3, fxb3,
                                   feW1, feb1, out, p, base1);
}

// Round 6
// 1622.283 us; speedup vs baseline: 1.0144x; 1.0144x over previous
//
#include <hip/hip_runtime.h>

// MsgPassingNN: 3 rounds of edge-MLP + segment_sum + node-MLP.
// N=100000 nodes (D=16), E=3200000 edges.
// fe: 32 -> 9 (relu) -> 9 (relu) -> 9 ; fx: 25 -> 9 (relu) -> 9 (relu) -> 16
//
// R5 structure (= R4 with the cache regression reverted):
//   Build: bucket sort by dst>>7 (782 buckets) with LDS-staged scatter.
//   Round: one block per bucket (512 thr), batch-4 edges per LDS weight fetch
//   (padded-12 rows -> float4 LDS reads, 0 bank conflicts measured in R4),
//   lacc stride 13, zero global atomics, plain-store drain.
//   KEY: p and base1 are TIGHT 9-float rows (3.6 MB each). p is gathered
//   uniformly-random by all XCDs -> must fit the 4 MiB per-XCD L2 (R4's
//   12-padded p + global base1 = 9.6 MB thrashed it: FETCH 35 MB -> 774 MB).
//   base1 gathers are block-local (128 rows = 4.6 KB, L1-hot).

constexpr int NN = 100000;
constexpr int NE = 3200000;
constexpr int NB = 782;                    // buckets of 128 nodes
constexpr int NBLD = (NE + 4095) / 4096;   // 782 build blocks, 4096 edges each

typedef float float4a __attribute__((ext_vector_type(4), aligned(4)));

// ---------------- build ----------------

__global__ __launch_bounds__(256) void h1_k(const int* __restrict__ dst,
                                            int* __restrict__ gcnt,
                                            int* __restrict__ bbase)
{
    __shared__ int lcnt[NB];
    const int t = threadIdx.x;
    for (int i = t; i < NB; i += 256) lcnt[i] = 0;
    __syncthreads();
    const int e0 = blockIdx.x * 4096;
    const int e1 = min(e0 + 4096, NE);
    for (int e = e0 + t; e < e1; e += 256) atomicAdd(&lcnt[dst[e] >> 7], 1);
    __syncthreads();
    for (int b = t; b < NB; b += 256) {
        int c = lcnt[b];
        bbase[blockIdx.x * NB + b] = c ? atomicAdd(&gcnt[b], c) : 0;
    }
}

__global__ __launch_bounds__(1024) void scan_k(const int* __restrict__ gcnt,
                                               int* __restrict__ bstart)
{
    __shared__ int s[1024];
    const int t = threadIdx.x;
    int v = (t < NB) ? gcnt[t] : 0;
    s[t] = v;
    __syncthreads();
    for (int off = 1; off < 1024; off <<= 1) {
        int a = (t >= off) ? s[t - off] : 0;
        __syncthreads();
        s[t] += a;
        __syncthreads();
    }
    if (t < NB) bstart[t + 1] = s[t];
    if (t == 0) bstart[0] = 0;
}

__global__ __launch_bounds__(256) void s1_k(const int* __restrict__ src,
                                            const int* __restrict__ dst,
                                            const int* __restrict__ bstart,
                                            const int* __restrict__ bbase,
                                            unsigned long long* __restrict__ sed2)
{
    __shared__ int lcnt[NB];
    __shared__ int sA[NB], sB[NB];
    __shared__ unsigned long long lbuf[4096];
    const int t = threadIdx.x;
    for (int i = t; i < NB; i += 256) lcnt[i] = 0;
    __syncthreads();
    const int e0 = blockIdx.x * 4096;
    const int n = min(4096, NE - e0);

    int dd[16], ss[16], rr[16];
    #pragma unroll
    for (int k = 0; k < 16; ++k) {
        int e = e0 + k * 256 + t;
        if (e < e0 + n) {
            dd[k] = dst[e]; ss[k] = src[e];
            rr[k] = atomicAdd(&lcnt[dd[k] >> 7], 1);
        }
    }
    __syncthreads();
    for (int i = t; i < NB; i += 256) sA[i] = lcnt[i];
    __syncthreads();
    int* pin = sA; int* pout = sB;
    for (int off = 1; off < NB; off <<= 1) {
        for (int i = t; i < NB; i += 256)
            pout[i] = pin[i] + ((i >= off) ? pin[i - off] : 0);
        __syncthreads();
        int* tmp = pin; pin = pout; pout = tmp;
    }
    #pragma unroll
    for (int k = 0; k < 16; ++k) {
        int e = e0 + k * 256 + t;
        if (e < e0 + n) {
            int b = dd[k] >> 7;
            int pos = pin[b] - lcnt[b] + rr[k];
            lbuf[pos] = ((unsigned long long)(unsigned)dd[k] << 32) | (unsigned)ss[k];
        }
    }
    __syncthreads();
    for (int i = t; i < n; i += 256) {
        unsigned long long pl = lbuf[i];
        int d = (int)(pl >> 32);
        int b = d >> 7;
        int pos = bstart[b] + bbase[blockIdx.x * NB + b] + (i - (pin[b] - lcnt[b]));
        sed2[pos] = pl;
    }
}

// ---------------- init: p, base1 from X0 (tight 9-float rows) ----------------

__global__ __launch_bounds__(512) void init5_k(const float* __restrict__ X,
                                               const float* __restrict__ feW1,
                                               const float* __restrict__ feb1,
                                               float* __restrict__ p,
                                               float* __restrict__ base1)
{
    __shared__ float sWd[144], sWs[144], sb1[9];
    const int t = threadIdx.x;
    if (t < 144) { sWd[t] = feW1[t]; sWs[t] = feW1[144 + t]; }
    if (t < 9) sb1[t] = feb1[t];
    __syncthreads();
    const int nidx = blockIdx.x * 512 + t;
    if (nidx >= NN) return;
    float x[16];
    const float4* q = reinterpret_cast<const float4*>(X + (size_t)nidx * 16);
    #pragma unroll
    for (int k = 0; k < 4; ++k) {
        float4 v = q[k];
        x[4*k] = v.x; x[4*k+1] = v.y; x[4*k+2] = v.z; x[4*k+3] = v.w;
    }
    float a[9], b[9];
    #pragma unroll
    for (int j = 0; j < 9; ++j) { a[j] = 0.f; b[j] = sb1[j]; }
    #pragma unroll
    for (int i = 0; i < 16; ++i) {
        const float xi = x[i];
        #pragma unroll
        for (int j = 0; j < 9; ++j) {
            a[j] = fmaf(xi, sWs[i * 9 + j], a[j]);
            b[j] = fmaf(xi, sWd[i * 9 + j], b[j]);
        }
    }
    float* pp = p + (size_t)nidx * 9;
    float* bp = base1 + (size_t)nidx * 9;
    #pragma unroll
    for (int j = 0; j < 9; ++j) { pp[j] = a[j]; bp[j] = b[j]; }
}

// ---------------- edge round: one block per bucket, batch-4 ----------------

__global__ __launch_bounds__(512) void round5_k(
    const unsigned long long* __restrict__ sed2,
    const int* __restrict__ bstart,
    const float* __restrict__ p,
    const float* __restrict__ base1,
    const float* __restrict__ feW2, const float* __restrict__ feb2,
    const float* __restrict__ feW3, const float* __restrict__ feb3,
    float* __restrict__ m)
{
    __shared__ __align__(16) float sW2[9 * 12], sW3[9 * 12];
    __shared__ float sb2s[9], sb3s[9];
    __shared__ float lacc[128 * 13];   // stride 13: odd -> all 32 banks
    const int t = threadIdx.x;
    if (t < 108) {
        int r = t / 12, c = t % 12;
        sW2[t] = (c < 9) ? feW2[r * 9 + c] : 0.f;
        sW3[t] = (c < 9) ? feW3[r * 9 + c] : 0.f;
    }
    if (t >= 128 && t < 137) sb2s[t - 128] = feb2[t - 128];
    if (t >= 160 && t < 169) sb3s[t - 160] = feb3[t - 160];
    for (int i = t; i < 128 * 13; i += 512) lacc[i] = 0.f;
    __syncthreads();

    const int e0 = bstart[blockIdx.x];
    const int e1 = bstart[blockIdx.x + 1];

    for (int base = e0 + t * 4; base < e1; base += 512 * 4) {
        if (base + 4 <= e1) {
            unsigned long long pk[4];
            const uint4* sp = reinterpret_cast<const uint4*>(sed2 + base);
            uint4 u0 = sp[0], u1 = sp[1];
            pk[0] = ((unsigned long long)u0.y << 32) | u0.x;
            pk[1] = ((unsigned long long)u0.w << 32) | u0.z;
            pk[2] = ((unsigned long long)u1.y << 32) | u1.x;
            pk[3] = ((unsigned long long)u1.w << 32) | u1.z;

            int ld[4];
            float A[4][9];
            #pragma unroll
            for (int k = 0; k < 4; ++k) {
                const int d = (int)(pk[k] >> 32);
                const int s = (int)(pk[k] & 0xffffffffu);
                ld[k] = d & 127;
                const float* pp = p + (size_t)s * 9;
                const float* bb = base1 + (size_t)d * 9;
                float4a pa = *(const float4a*)pp;
                float4a pb = *(const float4a*)(pp + 4);
                float   pc = pp[8];
                float4a ba = *(const float4a*)bb;
                float4a bc4 = *(const float4a*)(bb + 4);
                float   bc = bb[8];
                A[k][0] = fmaxf(pa.x + ba.x, 0.f);
                A[k][1] = fmaxf(pa.y + ba.y, 0.f);
                A[k][2] = fmaxf(pa.z + ba.z, 0.f);
                A[k][3] = fmaxf(pa.w + ba.w, 0.f);
                A[k][4] = fmaxf(pb.x + bc4.x, 0.f);
                A[k][5] = fmaxf(pb.y + bc4.y, 0.f);
                A[k][6] = fmaxf(pb.z + bc4.z, 0.f);
                A[k][7] = fmaxf(pb.w + bc4.w, 0.f);
                A[k][8] = fmaxf(pc + bc, 0.f);
            }

            float H[4][9];
            #pragma unroll
            for (int k = 0; k < 4; ++k)
                #pragma unroll
                for (int j = 0; j < 9; ++j) H[k][j] = sb2s[j];
            #pragma unroll
            for (int i = 0; i < 9; ++i) {
                float4 wa = *(const float4*)(sW2 + i * 12);
                float4 wb = *(const float4*)(sW2 + i * 12 + 4);
                float  wc = sW2[i * 12 + 8];
                #pragma unroll
                for (int k = 0; k < 4; ++k) {
                    const float x = A[k][i];
                    H[k][0] = fmaf(x, wa.x, H[k][0]);
                    H[k][1] = fmaf(x, wa.y, H[k][1]);
                    H[k][2] = fmaf(x, wa.z, H[k][2]);
                    H[k][3] = fmaf(x, wa.w, H[k][3]);
                    H[k][4] = fmaf(x, wb.x, H[k][4]);
                    H[k][5] = fmaf(x, wb.y, H[k][5]);
                    H[k][6] = fmaf(x, wb.z, H[k][6]);
                    H[k][7] = fmaf(x, wb.w, H[k][7]);
                    H[k][8] = fmaf(x, wc,   H[k][8]);
                }
            }
            #pragma unroll
            for (int k = 0; k < 4; ++k)
                #pragma unroll
                for (int j = 0; j < 9; ++j) H[k][j] = fmaxf(H[k][j], 0.f);

            float O[4][9];
            #pragma unroll
            for (int k = 0; k < 4; ++k)
                #pragma unroll
                for (int j = 0; j < 9; ++j) O[k][j] = sb3s[j];
            #pragma unroll
            for (int i = 0; i < 9; ++i) {
                float4 wa = *(const float4*)(sW3 + i * 12);
                float4 wb = *(const float4*)(sW3 + i * 12 + 4);
                float  wc = sW3[i * 12 + 8];
                #pragma unroll
                for (int k = 0; k < 4; ++k) {
                    const float x = H[k][i];
                    O[k][0] = fmaf(x, wa.x, O[k][0]);
                    O[k][1] = fmaf(x, wa.y, O[k][1]);
                    O[k][2] = fmaf(x, wa.z, O[k][2]);
                    O[k][3] = fmaf(x, wa.w, O[k][3]);
                    O[k][4] = fmaf(x, wb.x, O[k][4]);
                    O[k][5] = fmaf(x, wb.y, O[k][5]);
                    O[k][6] = fmaf(x, wb.z, O[k][6]);
                    O[k][7] = fmaf(x, wb.w, O[k][7]);
                    O[k][8] = fmaf(x, wc,   O[k][8]);
                }
            }
            #pragma unroll
            for (int k = 0; k < 4; ++k) {
                float* lp = lacc + ld[k] * 13;
                #pragma unroll
                for (int j = 0; j < 9; ++j) atomicAdd(lp + j, O[k][j]);
            }
        } else {
            for (int e = base; e < e1; ++e) {
                const unsigned long long pkv = sed2[e];
                const int d = (int)(pkv >> 32);
                const int s = (int)(pkv & 0xffffffffu);
                const int l = d & 127;
                const float* pp = p + (size_t)s * 9;
                const float* bb = base1 + (size_t)d * 9;
                float a[9];
                #pragma unroll
                for (int j = 0; j < 9; ++j) a[j] = fmaxf(pp[j] + bb[j], 0.f);
                float h[9];
                #pragma unroll
                for (int j = 0; j < 9; ++j) h[j] = sb2s[j];
                #pragma unroll
                for (int i = 0; i < 9; ++i) {
                    const float x = a[i];
                    #pragma unroll
                    for (int j = 0; j < 9; ++j) h[j] = fmaf(x, sW2[i * 12 + j], h[j]);
                }
                #pragma unroll
                for (int j = 0; j < 9; ++j) h[j] = fmaxf(h[j], 0.f);
                float o[9];
                #pragma unroll
                for (int j = 0; j < 9; ++j) o[j] = sb3s[j];
                #pragma unroll
                for (int i = 0; i < 9; ++i) {
                    const float x = h[i];
                    #pragma unroll
                    for (int j = 0; j < 9; ++j) o[j] = fmaf(x, sW3[i * 12 + j], o[j]);
                }
                float* lp = lacc + l * 13;
                #pragma unroll
                for (int j = 0; j < 9; ++j) atomicAdd(lp + j, o[j]);
            }
        }
    }
    __syncthreads();

    const int node0 = blockIdx.x << 7;
    const int nn = min(128, NN - node0);
    for (int r = t; r < nn; r += 512) {
        const float* lp = lacc + r * 13;
        float v0 = lp[0], v1 = lp[1], v2 = lp[2], v3 = lp[3];
        float v4 = lp[4], v5 = lp[5], v6 = lp[6], v7 = lp[7], v8 = lp[8];
        float* mp = m + (size_t)(node0 + r) * 12;
        float4 w0; w0.x = v0; w0.y = v1; w0.z = v2; w0.w = v3;
        float4 w1; w1.x = v4; w1.y = v5; w1.z = v6; w1.w = v7;
        ((float4*)mp)[0] = w0;
        ((float4*)mp)[1] = w1;
        mp[8] = v8;
    }
}

// ---------------- node round: fx MLP + next p/base1 ----------------

__global__ __launch_bounds__(512) void node5_k(
    const float* __restrict__ Xin, const float* __restrict__ m,
    const float* __restrict__ fxW1, const float* __restrict__ fxb1,
    const float* __restrict__ fxW2, const float* __restrict__ fxb2,
    const float* __restrict__ fxW3, const float* __restrict__ fxb3,
    const float* __restrict__ feW1, const float* __restrict__ feb1,
    float* __restrict__ Xout, float* __restrict__ p, float* __restrict__ base1)
{
    __shared__ float sU1[225], sU2[81], sU3[144];
    __shared__ float sWd[144], sWs[144];
    __shared__ float snb[34], sb1[9];
    const int t = threadIdx.x;
    if (t < 225) sU1[t] = fxW1[t];
    if (t < 81)  sU2[t] = fxW2[t];
    if (t < 144) { sU3[t] = fxW3[t]; sWd[t] = feW1[t]; sWs[t] = feW1[144 + t]; }
    if (t < 9) { snb[t] = fxb1[t]; snb[9 + t] = fxb2[t]; sb1[t] = feb1[t]; }
    if (t >= 32 && t < 48) snb[18 + (t - 32)] = fxb3[t - 32];
    __syncthreads();

    const int n = blockIdx.x * 512 + t;
    if (n >= NN) return;

    float xr[16];
    const float4* q = reinterpret_cast<const float4*>(Xin + (size_t)n * 16);
    #pragma unroll
    for (int k = 0; k < 4; ++k) {
        float4 v = q[k];
        xr[4*k] = v.x; xr[4*k+1] = v.y; xr[4*k+2] = v.z; xr[4*k+3] = v.w;
    }
    float mm[9];
    const float* mp = m + (size_t)n * 12;
    {
        float4 a = *(const float4*)mp;
        float4 b = *(const float4*)(mp + 4);
        mm[0] = a.x; mm[1] = a.y; mm[2] = a.z; mm[3] = a.w;
        mm[4] = b.x; mm[5] = b.y; mm[6] = b.z; mm[7] = b.w;
        mm[8] = mp[8];
    }

    float h1[9];
    #pragma unroll
    for (int j = 0; j < 9; ++j) h1[j] = snb[j];
    #pragma unroll
    for (int i = 0; i < 16; ++i) {
        const float xi = xr[i];
        #pragma unroll
        for (int j = 0; j < 9; ++j) h1[j] = fmaf(xi, sU1[i * 9 + j], h1[j]);
    }
    #pragma unroll
    for (int i = 0; i < 9; ++i) {
        const float xi = mm[i];
        #pragma unroll
        for (int j = 0; j < 9; ++j) h1[j] = fmaf(xi, sU1[(16 + i) * 9 + j], h1[j]);
    }
    #pragma unroll
    for (int j = 0; j < 9; ++j) h1[j] = fmaxf(h1[j], 0.f);

    float h2[9];
    #pragma unroll
    for (int j = 0; j < 9; ++j) h2[j] = snb[9 + j];
    #pragma unroll
    for (int i = 0; i < 9; ++i) {
        const float xi = h1[i];
        #pragma unroll
        for (int j = 0; j < 9; ++j) h2[j] = fmaf(xi, sU2[i * 9 + j], h2[j]);
    }
    #pragma unroll
    for (int j = 0; j < 9; ++j) h2[j] = fmaxf(h2[j], 0.f);

    float o[16];
    #pragma unroll
    for (int k = 0; k < 16; ++k) o[k] = snb[18 + k];
    #pragma unroll
    for (int j = 0; j < 9; ++j) {
        const float hj = h2[j];
        #pragma unroll
        for (int k = 0; k < 16; ++k) o[k] = fmaf(hj, sU3[j * 16 + k], o[k]);
    }

    float4* po = reinterpret_cast<float4*>(Xout + (size_t)n * 16);
    #pragma unroll
    for (int k = 0; k < 4; ++k) {
        float4 v;
        v.x = o[4*k]; v.y = o[4*k+1]; v.z = o[4*k+2]; v.w = o[4*k+3];
        po[k] = v;
    }

    float a[9], b[9];
    #pragma unroll
    for (int j = 0; j < 9; ++j) { a[j] = 0.f; b[j] = sb1[j]; }
    #pragma unroll
    for (int i = 0; i < 16; ++i) {
        const float xi = o[i];
        #pragma unroll
        for (int j = 0; j < 9; ++j) {
            a[j] = fmaf(xi, sWs[i * 9 + j], a[j]);
            b[j] = fmaf(xi, sWd[i * 9 + j], b[j]);
        }
    }
    float* pp = p + (size_t)n * 9;
    float* bp = base1 + (size_t)n * 9;
    #pragma unroll
    for (int j = 0; j < 9; ++j) { pp[j] = a[j]; bp[j] = b[j]; }
}

extern "C" void kernel_launch(void* const* d_in, const int* in_sizes, int n_in,
                              void* d_out, int out_size, void* d_ws, size_t ws_size,
                              hipStream_t stream)
{
    const float* X0   = (const float*)d_in[0];
    const int*   esrc = (const int*)d_in[1];
    const int*   edst = (const int*)d_in[2];
    const float* feW1 = (const float*)d_in[3];
    const float* feb1 = (const float*)d_in[4];
    const float* feW2 = (const float*)d_in[5];
    const float* feb2 = (const float*)d_in[6];
    const float* feW3 = (const float*)d_in[7];
    const float* feb3 = (const float*)d_in[8];
    const float* fxW1 = (const float*)d_in[9];
    const float* fxb1 = (const float*)d_in[10];
    const float* fxW2 = (const float*)d_in[11];
    const float* fxb2 = (const float*)d_in[12];
    const float* fxW3 = (const float*)d_in[13];
    const float* fxb3 = (const float*)d_in[14];
    float* out = (float*)d_out;

    // workspace (4B units); sed2 first for 16B alignment
    unsigned long long* sed2 = (unsigned long long*)d_ws;       // NE u64
    float* Xa    = (float*)(sed2 + NE);                         // NN*16
    float* Xb    = Xa + (size_t)NN * 16;                        // NN*16
    float* p     = Xb + (size_t)NN * 16;                        // NN*9 (tight!)
    float* base1 = p + (size_t)NN * 9;                          // NN*9 (tight!)
    float* mb    = base1 + (size_t)NN * 9;                      // NN*12
    int* gcnt    = (int*)(mb + (size_t)NN * 12);                // NB (+pad)
    int* bstart  = gcnt + (NB + 2);                             // NB+1 (+pad)
    int* bbase   = bstart + (NB + 2);                           // NBLD*NB

    const dim3 gB(NBLD), tB(256);
    const dim3 gN((NN + 511) / 512), tN(512);
    const dim3 gR(NB), tR(512);

    // ---- build (once per launch) ----
    hipMemsetAsync(gcnt, 0, (size_t)NB * sizeof(int), stream);
    h1_k<<<gB, tB, 0, stream>>>(edst, gcnt, bbase);
    scan_k<<<1, 1024, 0, stream>>>(gcnt, bstart);
    s1_k<<<gB, tB, 0, stream>>>(esrc, edst, bstart, bbase, sed2);

    // ---- rounds: X0 -> Xa -> Xb -> out ----
    init5_k<<<gN, tN, 0, stream>>>(X0, feW1, feb1, p, base1);

    round5_k<<<gR, tR, 0, stream>>>(sed2, bstart, p, base1,
                                    feW2, feb2, feW3, feb3, mb);
    node5_k<<<gN, tN, 0, stream>>>(X0, mb, fxW1, fxb1, fxW2, fxb2, fxW3, fxb3,
                                   feW1, feb1, Xa, p, base1);

    round5_k<<<gR, tR, 0, stream>>>(sed2, bstart, p, base1,
                                    feW2, feb2, feW3, feb3, mb);
    node5_k<<<gN, tN, 0, stream>>>(Xa, mb, fxW1, fxb1, fxW2, fxb2, fxW3, fxb3,
                                   feW1, feb1, Xb, p, base1);

    round5_k<<<gR, tR, 0, stream>>>(sed2, bstart, p, base1,
                                    feW2, feb2, feW3, feb3, mb);
    node5_k<<<gN, tN, 0, stream>>>(Xb, mb, fxW1, fxb1, fxW2, fxb2, fxW3, fxb3,
                                   feW1, feb1, out, p, base1);
}

// Round 7
// 1347.347 us; speedup vs baseline: 1.2214x; 1.2041x over previous
//
#include <hip/hip_runtime.h>

// MsgPassingNN: 3 rounds of edge-MLP + segment_sum + node-MLP.
// N=100000 nodes (D=16), E=3200000 edges.
// fe: 32 -> 9 (relu) -> 9 (relu) -> 9 ; fx: 25 -> 9 (relu) -> 9 (relu) -> 16
//
// R6: R5 with the REAL regression fixed. R4/R5's batch-4 edge path spilled
// (counters: WRITE_SIZE 345 MB vs 4.8 MB of real writes = scratch traffic;
// VGPR_Count pinned at 128 while live set A/H/O = 108 floats). Batch-2 keeps
// the live set ~60 floats -> no spill (R3 evidence: batch-2 = VGPR 104,
// WRITE 6 MB). Keep R4/R5's verified-good LDS layout: weight rows padded to
// 12 floats (ds_read_b128, 0 conflicts measured), lacc stride 13, zero
// global atomics, plain-store drain. sed packed to u32 (ld<<17|src).

constexpr int NN = 100000;
constexpr int NE = 3200000;
constexpr int NB = 782;                    // buckets of 128 nodes
constexpr int NBLD = (NE + 4095) / 4096;   // 782 build blocks, 4096 edges each

typedef float float4a __attribute__((ext_vector_type(4), aligned(4)));
typedef unsigned uint2a __attribute__((ext_vector_type(2), aligned(4)));

// ---------------- build ----------------

__global__ __launch_bounds__(256) void h1_k(const int* __restrict__ dst,
                                            int* __restrict__ gcnt,
                                            int* __restrict__ bbase)
{
    __shared__ int lcnt[NB];
    const int t = threadIdx.x;
    for (int i = t; i < NB; i += 256) lcnt[i] = 0;
    __syncthreads();
    const int e0 = blockIdx.x * 4096;
    const int e1 = min(e0 + 4096, NE);
    for (int e = e0 + t; e < e1; e += 256) atomicAdd(&lcnt[dst[e] >> 7], 1);
    __syncthreads();
    for (int b = t; b < NB; b += 256) {
        int c = lcnt[b];
        bbase[blockIdx.x * NB + b] = c ? atomicAdd(&gcnt[b], c) : 0;
    }
}

__global__ __launch_bounds__(1024) void scan_k(const int* __restrict__ gcnt,
                                               int* __restrict__ bstart)
{
    __shared__ int s[1024];
    const int t = threadIdx.x;
    int v = (t < NB) ? gcnt[t] : 0;
    s[t] = v;
    __syncthreads();
    for (int off = 1; off < 1024; off <<= 1) {
        int a = (t >= off) ? s[t - off] : 0;
        __syncthreads();
        s[t] += a;
        __syncthreads();
    }
    if (t < NB) bstart[t + 1] = s[t];
    if (t == 0) bstart[0] = 0;
}

__global__ __launch_bounds__(256) void s1_k(const int* __restrict__ src,
                                            const int* __restrict__ dst,
                                            const int* __restrict__ bstart,
                                            const int* __restrict__ bbase,
                                            unsigned* __restrict__ sed)
{
    __shared__ int lcnt[NB];
    __shared__ int sA[NB], sB[NB];
    __shared__ unsigned long long lbuf[4096];
    const int t = threadIdx.x;
    for (int i = t; i < NB; i += 256) lcnt[i] = 0;
    __syncthreads();
    const int e0 = blockIdx.x * 4096;
    const int n = min(4096, NE - e0);

    int dd[16], ss[16], rr[16];
    #pragma unroll
    for (int k = 0; k < 16; ++k) {
        int e = e0 + k * 256 + t;
        if (e < e0 + n) {
            dd[k] = dst[e]; ss[k] = src[e];
            rr[k] = atomicAdd(&lcnt[dd[k] >> 7], 1);
        }
    }
    __syncthreads();
    for (int i = t; i < NB; i += 256) sA[i] = lcnt[i];
    __syncthreads();
    int* pin = sA; int* pout = sB;
    for (int off = 1; off < NB; off <<= 1) {
        for (int i = t; i < NB; i += 256)
            pout[i] = pin[i] + ((i >= off) ? pin[i - off] : 0);
        __syncthreads();
        int* tmp = pin; pin = pout; pout = tmp;
    }
    #pragma unroll
    for (int k = 0; k < 16; ++k) {
        int e = e0 + k * 256 + t;
        if (e < e0 + n) {
            int b = dd[k] >> 7;
            int pos = pin[b] - lcnt[b] + rr[k];
            lbuf[pos] = ((unsigned long long)(unsigned)dd[k] << 32) | (unsigned)ss[k];
        }
    }
    __syncthreads();
    for (int i = t; i < n; i += 256) {
        unsigned long long pl = lbuf[i];
        int d = (int)(pl >> 32);
        int b = d >> 7;
        int pos = bstart[b] + bbase[blockIdx.x * NB + b] + (i - (pin[b] - lcnt[b]));
        sed[pos] = ((unsigned)(d & 127) << 17) | (unsigned)(pl & 0x1FFFFu);
    }
}

// ---------------- init: p, base1 from X0 (tight 9-float rows) ----------------

__global__ __launch_bounds__(512) void init6_k(const float* __restrict__ X,
                                               const float* __restrict__ feW1,
                                               const float* __restrict__ feb1,
                                               float* __restrict__ p,
                                               float* __restrict__ base1)
{
    __shared__ float sWd[144], sWs[144], sb1[9];
    const int t = threadIdx.x;
    if (t < 144) { sWd[t] = feW1[t]; sWs[t] = feW1[144 + t]; }
    if (t < 9) sb1[t] = feb1[t];
    __syncthreads();
    const int nidx = blockIdx.x * 512 + t;
    if (nidx >= NN) return;
    float x[16];
    const float4* q = reinterpret_cast<const float4*>(X + (size_t)nidx * 16);
    #pragma unroll
    for (int k = 0; k < 4; ++k) {
        float4 v = q[k];
        x[4*k] = v.x; x[4*k+1] = v.y; x[4*k+2] = v.z; x[4*k+3] = v.w;
    }
    float a[9], b[9];
    #pragma unroll
    for (int j = 0; j < 9; ++j) { a[j] = 0.f; b[j] = sb1[j]; }
    #pragma unroll
    for (int i = 0; i < 16; ++i) {
        const float xi = x[i];
        #pragma unroll
        for (int j = 0; j < 9; ++j) {
            a[j] = fmaf(xi, sWs[i * 9 + j], a[j]);
            b[j] = fmaf(xi, sWd[i * 9 + j], b[j]);
        }
    }
    float* pp = p + (size_t)nidx * 9;
    float* bp = base1 + (size_t)nidx * 9;
    #pragma unroll
    for (int j = 0; j < 9; ++j) { pp[j] = a[j]; bp[j] = b[j]; }
}

// ---------------- edge round: one block per bucket, batch-2 ----------------

__global__ __launch_bounds__(512) void round6_k(
    const unsigned* __restrict__ sed,
    const int* __restrict__ bstart,
    const float* __restrict__ p,
    const float* __restrict__ base1,
    const float* __restrict__ feW2, const float* __restrict__ feb2,
    const float* __restrict__ feW3, const float* __restrict__ feb3,
    float* __restrict__ m)
{
    __shared__ __align__(16) float sW2[9 * 12], sW3[9 * 12];
    __shared__ float sb2s[9], sb3s[9];
    __shared__ float lacc[128 * 13];   // stride 13: odd -> all 32 banks
    const int t = threadIdx.x;
    if (t < 108) {
        int r = t / 12, c = t % 12;
        sW2[t] = (c < 9) ? feW2[r * 9 + c] : 0.f;
        sW3[t] = (c < 9) ? feW3[r * 9 + c] : 0.f;
    }
    if (t >= 128 && t < 137) sb2s[t - 128] = feb2[t - 128];
    if (t >= 160 && t < 169) sb3s[t - 160] = feb3[t - 160];
    for (int i = t; i < 128 * 13; i += 512) lacc[i] = 0.f;
    __syncthreads();

    const int e0 = bstart[blockIdx.x];
    const int e1 = bstart[blockIdx.x + 1];
    const int node0 = blockIdx.x << 7;

    for (int base = e0 + t * 2; base < e1; base += 1024) {
        if (base + 2 <= e1) {
            // ---- pair path ----
            uint2a uu = *(const uint2a*)(sed + base);
            const unsigned pk0 = uu.x, pk1 = uu.y;
            const int ld0 = (int)(pk0 >> 17), s0 = (int)(pk0 & 0x1FFFFu);
            const int ld1 = (int)(pk1 >> 17), s1 = (int)(pk1 & 0x1FFFFu);

            const float* pp0 = p + (size_t)s0 * 9;
            const float* pp1 = p + (size_t)s1 * 9;
            const float* bb0 = base1 + (size_t)(node0 + ld0) * 9;
            const float* bb1 = base1 + (size_t)(node0 + ld1) * 9;

            float4a pa0 = *(const float4a*)pp0;
            float4a pb0 = *(const float4a*)(pp0 + 4);
            float   pc0 = pp0[8];
            float4a ba0 = *(const float4a*)bb0;
            float4a bq0 = *(const float4a*)(bb0 + 4);
            float   bc0 = bb0[8];
            float4a pa1 = *(const float4a*)pp1;
            float4a pb1 = *(const float4a*)(pp1 + 4);
            float   pc1 = pp1[8];
            float4a ba1 = *(const float4a*)bb1;
            float4a bq1 = *(const float4a*)(bb1 + 4);
            float   bc1 = bb1[8];

            float A0[9], A1[9];
            A0[0] = fmaxf(pa0.x + ba0.x, 0.f); A1[0] = fmaxf(pa1.x + ba1.x, 0.f);
            A0[1] = fmaxf(pa0.y + ba0.y, 0.f); A1[1] = fmaxf(pa1.y + ba1.y, 0.f);
            A0[2] = fmaxf(pa0.z + ba0.z, 0.f); A1[2] = fmaxf(pa1.z + ba1.z, 0.f);
            A0[3] = fmaxf(pa0.w + ba0.w, 0.f); A1[3] = fmaxf(pa1.w + ba1.w, 0.f);
            A0[4] = fmaxf(pb0.x + bq0.x, 0.f); A1[4] = fmaxf(pb1.x + bq1.x, 0.f);
            A0[5] = fmaxf(pb0.y + bq0.y, 0.f); A1[5] = fmaxf(pb1.y + bq1.y, 0.f);
            A0[6] = fmaxf(pb0.z + bq0.z, 0.f); A1[6] = fmaxf(pb1.z + bq1.z, 0.f);
            A0[7] = fmaxf(pb0.w + bq0.w, 0.f); A1[7] = fmaxf(pb1.w + bq1.w, 0.f);
            A0[8] = fmaxf(pc0 + bc0, 0.f);     A1[8] = fmaxf(pc1 + bc1, 0.f);

            float H0[9], H1[9];
            #pragma unroll
            for (int j = 0; j < 9; ++j) { H0[j] = sb2s[j]; H1[j] = sb2s[j]; }
            #pragma unroll
            for (int i = 0; i < 9; ++i) {
                float4 wa = *(const float4*)(sW2 + i * 12);
                float4 wb = *(const float4*)(sW2 + i * 12 + 4);
                float  wc = sW2[i * 12 + 8];
                const float x0 = A0[i], x1 = A1[i];
                H0[0] = fmaf(x0, wa.x, H0[0]); H1[0] = fmaf(x1, wa.x, H1[0]);
                H0[1] = fmaf(x0, wa.y, H0[1]); H1[1] = fmaf(x1, wa.y, H1[1]);
                H0[2] = fmaf(x0, wa.z, H0[2]); H1[2] = fmaf(x1, wa.z, H1[2]);
                H0[3] = fmaf(x0, wa.w, H0[3]); H1[3] = fmaf(x1, wa.w, H1[3]);
                H0[4] = fmaf(x0, wb.x, H0[4]); H1[4] = fmaf(x1, wb.x, H1[4]);
                H0[5] = fmaf(x0, wb.y, H0[5]); H1[5] = fmaf(x1, wb.y, H1[5]);
                H0[6] = fmaf(x0, wb.z, H0[6]); H1[6] = fmaf(x1, wb.z, H1[6]);
                H0[7] = fmaf(x0, wb.w, H0[7]); H1[7] = fmaf(x1, wb.w, H1[7]);
                H0[8] = fmaf(x0, wc,   H0[8]); H1[8] = fmaf(x1, wc,   H1[8]);
            }
            #pragma unroll
            for (int j = 0; j < 9; ++j) { H0[j] = fmaxf(H0[j], 0.f); H1[j] = fmaxf(H1[j], 0.f); }

            float O0[9], O1[9];
            #pragma unroll
            for (int j = 0; j < 9; ++j) { O0[j] = sb3s[j]; O1[j] = sb3s[j]; }
            #pragma unroll
            for (int i = 0; i < 9; ++i) {
                float4 wa = *(const float4*)(sW3 + i * 12);
                float4 wb = *(const float4*)(sW3 + i * 12 + 4);
                float  wc = sW3[i * 12 + 8];
                const float x0 = H0[i], x1 = H1[i];
                O0[0] = fmaf(x0, wa.x, O0[0]); O1[0] = fmaf(x1, wa.x, O1[0]);
                O0[1] = fmaf(x0, wa.y, O0[1]); O1[1] = fmaf(x1, wa.y, O1[1]);
                O0[2] = fmaf(x0, wa.z, O0[2]); O1[2] = fmaf(x1, wa.z, O1[2]);
                O0[3] = fmaf(x0, wa.w, O0[3]); O1[3] = fmaf(x1, wa.w, O1[3]);
                O0[4] = fmaf(x0, wb.x, O0[4]); O1[4] = fmaf(x1, wb.x, O1[4]);
                O0[5] = fmaf(x0, wb.y, O0[5]); O1[5] = fmaf(x1, wb.y, O1[5]);
                O0[6] = fmaf(x0, wb.z, O0[6]); O1[6] = fmaf(x1, wb.z, O1[6]);
                O0[7] = fmaf(x0, wb.w, O0[7]); O1[7] = fmaf(x1, wb.w, O1[7]);
                O0[8] = fmaf(x0, wc,   O0[8]); O1[8] = fmaf(x1, wc,   O1[8]);
            }
            float* lp0 = lacc + ld0 * 13;
            float* lp1 = lacc + ld1 * 13;
            #pragma unroll
            for (int j = 0; j < 9; ++j) atomicAdd(lp0 + j, O0[j]);
            #pragma unroll
            for (int j = 0; j < 9; ++j) atomicAdd(lp1 + j, O1[j]);
        } else if (base < e1) {
            // ---- single-edge tail ----
            const unsigned pk = sed[base];
            const int l = (int)(pk >> 17), s = (int)(pk & 0x1FFFFu);
            const float* pp = p + (size_t)s * 9;
            const float* bb = base1 + (size_t)(node0 + l) * 9;
            float a[9];
            #pragma unroll
            for (int j = 0; j < 9; ++j) a[j] = fmaxf(pp[j] + bb[j], 0.f);
            float h[9];
            #pragma unroll
            for (int j = 0; j < 9; ++j) h[j] = sb2s[j];
            #pragma unroll
            for (int i = 0; i < 9; ++i) {
                const float x = a[i];
                #pragma unroll
                for (int j = 0; j < 9; ++j) h[j] = fmaf(x, sW2[i * 12 + j], h[j]);
            }
            #pragma unroll
            for (int j = 0; j < 9; ++j) h[j] = fmaxf(h[j], 0.f);
            float o[9];
            #pragma unroll
            for (int j = 0; j < 9; ++j) o[j] = sb3s[j];
            #pragma unroll
            for (int i = 0; i < 9; ++i) {
                const float x = h[i];
                #pragma unroll
                for (int j = 0; j < 9; ++j) o[j] = fmaf(x, sW3[i * 12 + j], o[j]);
            }
            float* lp = lacc + l * 13;
            #pragma unroll
            for (int j = 0; j < 9; ++j) atomicAdd(lp + j, o[j]);
        }
    }
    __syncthreads();

    const int nn = min(128, NN - node0);
    for (int r = t; r < nn; r += 512) {
        const float* lp = lacc + r * 13;
        float v0 = lp[0], v1 = lp[1], v2 = lp[2], v3 = lp[3];
        float v4 = lp[4], v5 = lp[5], v6 = lp[6], v7 = lp[7], v8 = lp[8];
        float* mp = m + (size_t)(node0 + r) * 12;
        float4 w0; w0.x = v0; w0.y = v1; w0.z = v2; w0.w = v3;
        float4 w1; w1.x = v4; w1.y = v5; w1.z = v6; w1.w = v7;
        ((float4*)mp)[0] = w0;
        ((float4*)mp)[1] = w1;
        mp[8] = v8;
    }
}

// ---------------- node round: fx MLP + next p/base1 ----------------

__global__ __launch_bounds__(512) void node6_k(
    const float* __restrict__ Xin, const float* __restrict__ m,
    const float* __restrict__ fxW1, const float* __restrict__ fxb1,
    const float* __restrict__ fxW2, const float* __restrict__ fxb2,
    const float* __restrict__ fxW3, const float* __restrict__ fxb3,
    const float* __restrict__ feW1, const float* __restrict__ feb1,
    float* __restrict__ Xout, float* __restrict__ p, float* __restrict__ base1)
{
    __shared__ float sU1[225], sU2[81], sU3[144];
    __shared__ float sWd[144], sWs[144];
    __shared__ float snb[34], sb1[9];
    const int t = threadIdx.x;
    if (t < 225) sU1[t] = fxW1[t];
    if (t < 81)  sU2[t] = fxW2[t];
    if (t < 144) { sU3[t] = fxW3[t]; sWd[t] = feW1[t]; sWs[t] = feW1[144 + t]; }
    if (t < 9) { snb[t] = fxb1[t]; snb[9 + t] = fxb2[t]; sb1[t] = feb1[t]; }
    if (t >= 32 && t < 48) snb[18 + (t - 32)] = fxb3[t - 32];
    __syncthreads();

    const int n = blockIdx.x * 512 + t;
    if (n >= NN) return;

    float xr[16];
    const float4* q = reinterpret_cast<const float4*>(Xin + (size_t)n * 16);
    #pragma unroll
    for (int k = 0; k < 4; ++k) {
        float4 v = q[k];
        xr[4*k] = v.x; xr[4*k+1] = v.y; xr[4*k+2] = v.z; xr[4*k+3] = v.w;
    }
    float mm[9];
    const float* mp = m + (size_t)n * 12;
    {
        float4 a = *(const float4*)mp;
        float4 b = *(const float4*)(mp + 4);
        mm[0] = a.x; mm[1] = a.y; mm[2] = a.z; mm[3] = a.w;
        mm[4] = b.x; mm[5] = b.y; mm[6] = b.z; mm[7] = b.w;
        mm[8] = mp[8];
    }

    float h1[9];
    #pragma unroll
    for (int j = 0; j < 9; ++j) h1[j] = snb[j];
    #pragma unroll
    for (int i = 0; i < 16; ++i) {
        const float xi = xr[i];
        #pragma unroll
        for (int j = 0; j < 9; ++j) h1[j] = fmaf(xi, sU1[i * 9 + j], h1[j]);
    }
    #pragma unroll
    for (int i = 0; i < 9; ++i) {
        const float xi = mm[i];
        #pragma unroll
        for (int j = 0; j < 9; ++j) h1[j] = fmaf(xi, sU1[(16 + i) * 9 + j], h1[j]);
    }
    #pragma unroll
    for (int j = 0; j < 9; ++j) h1[j] = fmaxf(h1[j], 0.f);

    float h2[9];
    #pragma unroll
    for (int j = 0; j < 9; ++j) h2[j] = snb[9 + j];
    #pragma unroll
    for (int i = 0; i < 9; ++i) {
        const float xi = h1[i];
        #pragma unroll
        for (int j = 0; j < 9; ++j) h2[j] = fmaf(xi, sU2[i * 9 + j], h2[j]);
    }
    #pragma unroll
    for (int j = 0; j < 9; ++j) h2[j] = fmaxf(h2[j], 0.f);

    float o[16];
    #pragma unroll
    for (int k = 0; k < 16; ++k) o[k] = snb[18 + k];
    #pragma unroll
    for (int j = 0; j < 9; ++j) {
        const float hj = h2[j];
        #pragma unroll
        for (int k = 0; k < 16; ++k) o[k] = fmaf(hj, sU3[j * 16 + k], o[k]);
    }

    float4* po = reinterpret_cast<float4*>(Xout + (size_t)n * 16);
    #pragma unroll
    for (int k = 0; k < 4; ++k) {
        float4 v;
        v.x = o[4*k]; v.y = o[4*k+1]; v.z = o[4*k+2]; v.w = o[4*k+3];
        po[k] = v;
    }

    float a[9], b[9];
    #pragma unroll
    for (int j = 0; j < 9; ++j) { a[j] = 0.f; b[j] = sb1[j]; }
    #pragma unroll
    for (int i = 0; i < 16; ++i) {
        const float xi = o[i];
        #pragma unroll
        for (int j = 0; j < 9; ++j) {
            a[j] = fmaf(xi, sWs[i * 9 + j], a[j]);
            b[j] = fmaf(xi, sWd[i * 9 + j], b[j]);
        }
    }
    float* pp = p + (size_t)n * 9;
    float* bp = base1 + (size_t)n * 9;
    #pragma unroll
    for (int j = 0; j < 9; ++j) { pp[j] = a[j]; bp[j] = b[j]; }
}

extern "C" void kernel_launch(void* const* d_in, const int* in_sizes, int n_in,
                              void* d_out, int out_size, void* d_ws, size_t ws_size,
                              hipStream_t stream)
{
    const float* X0   = (const float*)d_in[0];
    const int*   esrc = (const int*)d_in[1];
    const int*   edst = (const int*)d_in[2];
    const float* feW1 = (const float*)d_in[3];
    const float* feb1 = (const float*)d_in[4];
    const float* feW2 = (const float*)d_in[5];
    const float* feb2 = (const float*)d_in[6];
    const float* feW3 = (const float*)d_in[7];
    const float* feb3 = (const float*)d_in[8];
    const float* fxW1 = (const float*)d_in[9];
    const float* fxb1 = (const float*)d_in[10];
    const float* fxW2 = (const float*)d_in[11];
    const float* fxb2 = (const float*)d_in[12];
    const float* fxW3 = (const float*)d_in[13];
    const float* fxb3 = (const float*)d_in[14];
    float* out = (float*)d_out;

    // workspace (4B units)
    unsigned* sed = (unsigned*)d_ws;                            // NE u32
    float* Xa    = (float*)(sed + NE);                          // NN*16
    float* Xb    = Xa + (size_t)NN * 16;                        // NN*16
    float* p     = Xb + (size_t)NN * 16;                        // NN*9 (tight)
    float* base1 = p + (size_t)NN * 9;                          // NN*9 (tight)
    float* mb    = base1 + (size_t)NN * 9;                      // NN*12
    int* gcnt    = (int*)(mb + (size_t)NN * 12);                // NB (+pad)
    int* bstart  = gcnt + (NB + 2);                             // NB+1 (+pad)
    int* bbase   = bstart + (NB + 2);                           // NBLD*NB

    const dim3 gB(NBLD), tB(256);
    const dim3 gN((NN + 511) / 512), tN(512);
    const dim3 gR(NB), tR(512);

    // ---- build (once per launch) ----
    hipMemsetAsync(gcnt, 0, (size_t)NB * sizeof(int), stream);
    h1_k<<<gB, tB, 0, stream>>>(edst, gcnt, bbase);
    scan_k<<<1, 1024, 0, stream>>>(gcnt, bstart);
    s1_k<<<gB, tB, 0, stream>>>(esrc, edst, bstart, bbase, sed);

    // ---- rounds: X0 -> Xa -> Xb -> out ----
    init6_k<<<gN, tN, 0, stream>>>(X0, feW1, feb1, p, base1);

    round6_k<<<gR, tR, 0, stream>>>(sed, bstart, p, base1,
                                    feW2, feb2, feW3, feb3, mb);
    node6_k<<<gN, tN, 0, stream>>>(X0, mb, fxW1, fxb1, fxW2, fxb2, fxW3, fxb3,
                                   feW1, feb1, Xa, p, base1);

    round6_k<<<gR, tR, 0, stream>>>(sed, bstart, p, base1,
                                    feW2, feb2, feW3, feb3, mb);
    node6_k<<<gN, tN, 0, stream>>>(Xa, mb, fxW1, fxb1, fxW2, fxb2, fxW3, fxb3,
                                   feW1, feb1, Xb, p, base1);

    round6_k<<<gR, tR, 0, stream>>>(sed, bstart, p, base1,
                                    feW2, feb2, feW3, feb3, mb);
    node6_k<<<gN, tN, 0, stream>>>(Xb, mb, fxW1, fxb1, fxW2, fxb2, fxW3, fxb3,
                                   feW1, feb1, out, p, base1);
}

// Round 8
// 792.774 us; speedup vs baseline: 2.0758x; 1.6995x over previous
//
#include <hip/hip_runtime.h>

// MsgPassingNN: 3 rounds of edge-MLP + segment_sum + node-MLP.
// N=100000 nodes (D=16), E=3200000 edges.
// fe: 32 -> 9 (relu) -> 9 (relu) -> 9 ; fx: 25 -> 9 (relu) -> 9 (relu) -> 16
//
// R7: weights in REGISTERS, not LDS. Evidence trail: every 512-thread round
// kernel (R4/R5/R6) compiled to exactly VGPR_Count=128 and produced ~310-345MB
// of scratch write-through (real writes 4.8MB) -> the compiler caps 512-thread
// workgroups at 128 VGPRs and spills the MLP working set. Fix:
//   - 256-thread blocks, __launch_bounds__(256,2) -> 256-VGPR cap.
//   - W2/W3/b2/b3 (180 floats) preloaded to per-thread registers once per
//     block; batch-1 edge loop (register weights leave nothing to amortize).
//   - Zero DS reads in the loop; only 9 ds_add_f32 per edge into stride-13
//     lacc (odd stride -> all 32 banks; 0 conflicts measured since R4).
//   - p[src]/base1[dst] tight 9-float rows (3.6MB: p L2-resident, base1 rows
//     block-local = 4.6KB L1-hot). Plain-store drain, zero global atomics.

constexpr int NN = 100000;
constexpr int NE = 3200000;
constexpr int NB = 782;                    // buckets of 128 nodes
constexpr int NBLD = (NE + 4095) / 4096;   // 782 build blocks, 4096 edges each

typedef float float4a __attribute__((ext_vector_type(4), aligned(4)));

// ---------------- build ----------------

__global__ __launch_bounds__(256) void h1_k(const int* __restrict__ dst,
                                            int* __restrict__ gcnt,
                                            int* __restrict__ bbase)
{
    __shared__ int lcnt[NB];
    const int t = threadIdx.x;
    for (int i = t; i < NB; i += 256) lcnt[i] = 0;
    __syncthreads();
    const int e0 = blockIdx.x * 4096;
    const int e1 = min(e0 + 4096, NE);
    for (int e = e0 + t; e < e1; e += 256) atomicAdd(&lcnt[dst[e] >> 7], 1);
    __syncthreads();
    for (int b = t; b < NB; b += 256) {
        int c = lcnt[b];
        bbase[blockIdx.x * NB + b] = c ? atomicAdd(&gcnt[b], c) : 0;
    }
}

__global__ __launch_bounds__(1024) void scan_k(const int* __restrict__ gcnt,
                                               int* __restrict__ bstart)
{
    __shared__ int s[1024];
    const int t = threadIdx.x;
    int v = (t < NB) ? gcnt[t] : 0;
    s[t] = v;
    __syncthreads();
    for (int off = 1; off < 1024; off <<= 1) {
        int a = (t >= off) ? s[t - off] : 0;
        __syncthreads();
        s[t] += a;
        __syncthreads();
    }
    if (t < NB) bstart[t + 1] = s[t];
    if (t == 0) bstart[0] = 0;
}

__global__ __launch_bounds__(256) void s1_k(const int* __restrict__ src,
                                            const int* __restrict__ dst,
                                            const int* __restrict__ bstart,
                                            const int* __restrict__ bbase,
                                            unsigned* __restrict__ sed)
{
    __shared__ int lcnt[NB];
    __shared__ int sA[NB], sB[NB];
    __shared__ unsigned long long lbuf[4096];
    const int t = threadIdx.x;
    for (int i = t; i < NB; i += 256) lcnt[i] = 0;
    __syncthreads();
    const int e0 = blockIdx.x * 4096;
    const int n = min(4096, NE - e0);

    int dd[16], ss[16], rr[16];
    #pragma unroll
    for (int k = 0; k < 16; ++k) {
        int e = e0 + k * 256 + t;
        if (e < e0 + n) {
            dd[k] = dst[e]; ss[k] = src[e];
            rr[k] = atomicAdd(&lcnt[dd[k] >> 7], 1);
        }
    }
    __syncthreads();
    for (int i = t; i < NB; i += 256) sA[i] = lcnt[i];
    __syncthreads();
    int* pin = sA; int* pout = sB;
    for (int off = 1; off < NB; off <<= 1) {
        for (int i = t; i < NB; i += 256)
            pout[i] = pin[i] + ((i >= off) ? pin[i - off] : 0);
        __syncthreads();
        int* tmp = pin; pin = pout; pout = tmp;
    }
    #pragma unroll
    for (int k = 0; k < 16; ++k) {
        int e = e0 + k * 256 + t;
        if (e < e0 + n) {
            int b = dd[k] >> 7;
            int pos = pin[b] - lcnt[b] + rr[k];
            lbuf[pos] = ((unsigned long long)(unsigned)dd[k] << 32) | (unsigned)ss[k];
        }
    }
    __syncthreads();
    for (int i = t; i < n; i += 256) {
        unsigned long long pl = lbuf[i];
        int d = (int)(pl >> 32);
        int b = d >> 7;
        int pos = bstart[b] + bbase[blockIdx.x * NB + b] + (i - (pin[b] - lcnt[b]));
        sed[pos] = ((unsigned)(d & 127) << 17) | (unsigned)(pl & 0x1FFFFu);
    }
}

// ---------------- init: p, base1 from X0 (tight 9-float rows) ----------------

__global__ __launch_bounds__(512) void init7_k(const float* __restrict__ X,
                                               const float* __restrict__ feW1,
                                               const float* __restrict__ feb1,
                                               float* __restrict__ p,
                                               float* __restrict__ base1)
{
    __shared__ float sWd[144], sWs[144], sb1[9];
    const int t = threadIdx.x;
    if (t < 144) { sWd[t] = feW1[t]; sWs[t] = feW1[144 + t]; }
    if (t < 9) sb1[t] = feb1[t];
    __syncthreads();
    const int nidx = blockIdx.x * 512 + t;
    if (nidx >= NN) return;
    float x[16];
    const float4* q = reinterpret_cast<const float4*>(X + (size_t)nidx * 16);
    #pragma unroll
    for (int k = 0; k < 4; ++k) {
        float4 v = q[k];
        x[4*k] = v.x; x[4*k+1] = v.y; x[4*k+2] = v.z; x[4*k+3] = v.w;
    }
    float a[9], b[9];
    #pragma unroll
    for (int j = 0; j < 9; ++j) { a[j] = 0.f; b[j] = sb1[j]; }
    #pragma unroll
    for (int i = 0; i < 16; ++i) {
        const float xi = x[i];
        #pragma unroll
        for (int j = 0; j < 9; ++j) {
            a[j] = fmaf(xi, sWs[i * 9 + j], a[j]);
            b[j] = fmaf(xi, sWd[i * 9 + j], b[j]);
        }
    }
    float* pp = p + (size_t)nidx * 9;
    float* bp = base1 + (size_t)nidx * 9;
    #pragma unroll
    for (int j = 0; j < 9; ++j) { pp[j] = a[j]; bp[j] = b[j]; }
}

// ---------------- edge round: register weights, batch-1 ----------------

__global__ __launch_bounds__(256, 2) void round7_k(
    const unsigned* __restrict__ sed,
    const int* __restrict__ bstart,
    const float* __restrict__ p,
    const float* __restrict__ base1,
    const float* __restrict__ feW2, const float* __restrict__ feb2,
    const float* __restrict__ feW3, const float* __restrict__ feb3,
    float* __restrict__ m)
{
    __shared__ float lacc[128 * 13];   // stride 13: odd -> all 32 banks
    const int t = threadIdx.x;
    for (int i = t; i < 128 * 13; i += 256) lacc[i] = 0.f;

    // weights -> registers (uniform loads; compiler promotes to scalar regs
    // where it can, VGPRs otherwise; cap is 256 via launch_bounds(256,2))
    float rW2[81], rW3[81], rb2[9], rb3[9];
    #pragma unroll
    for (int i = 0; i < 81; ++i) { rW2[i] = feW2[i]; rW3[i] = feW3[i]; }
    #pragma unroll
    for (int j = 0; j < 9; ++j) { rb2[j] = feb2[j]; rb3[j] = feb3[j]; }
    __syncthreads();

    const int e0 = bstart[blockIdx.x];
    const int e1 = bstart[blockIdx.x + 1];
    const int node0 = blockIdx.x << 7;

    for (int e = e0 + t; e < e1; e += 256) {
        const unsigned pk = sed[e];
        const int ld = (int)(pk >> 17);
        const int s  = (int)(pk & 0x1FFFFu);

        const float* pp = p + (size_t)s * 9;
        const float* bb = base1 + (size_t)(node0 + ld) * 9;
        float4a pa = *(const float4a*)pp;
        float4a pb = *(const float4a*)(pp + 4);
        float   pc = pp[8];
        float4a ba = *(const float4a*)bb;
        float4a bq = *(const float4a*)(bb + 4);
        float   bc = bb[8];

        float A[9];
        A[0] = fmaxf(pa.x + ba.x, 0.f);
        A[1] = fmaxf(pa.y + ba.y, 0.f);
        A[2] = fmaxf(pa.z + ba.z, 0.f);
        A[3] = fmaxf(pa.w + ba.w, 0.f);
        A[4] = fmaxf(pb.x + bq.x, 0.f);
        A[5] = fmaxf(pb.y + bq.y, 0.f);
        A[6] = fmaxf(pb.z + bq.z, 0.f);
        A[7] = fmaxf(pb.w + bq.w, 0.f);
        A[8] = fmaxf(pc + bc, 0.f);

        float H[9];
        #pragma unroll
        for (int j = 0; j < 9; ++j) H[j] = rb2[j];
        #pragma unroll
        for (int i = 0; i < 9; ++i) {
            const float x = A[i];
            #pragma unroll
            for (int j = 0; j < 9; ++j) H[j] = fmaf(x, rW2[i * 9 + j], H[j]);
        }
        #pragma unroll
        for (int j = 0; j < 9; ++j) H[j] = fmaxf(H[j], 0.f);

        float O[9];
        #pragma unroll
        for (int j = 0; j < 9; ++j) O[j] = rb3[j];
        #pragma unroll
        for (int i = 0; i < 9; ++i) {
            const float x = H[i];
            #pragma unroll
            for (int j = 0; j < 9; ++j) O[j] = fmaf(x, rW3[i * 9 + j], O[j]);
        }

        float* lp = lacc + ld * 13;
        #pragma unroll
        for (int j = 0; j < 9; ++j) atomicAdd(lp + j, O[j]);
    }
    __syncthreads();

    // drain: plain stores (this block owns the whole bucket)
    const int nn = min(128, NN - node0);
    for (int r = t; r < nn; r += 256) {
        const float* lp = lacc + r * 13;
        float v0 = lp[0], v1 = lp[1], v2 = lp[2], v3 = lp[3];
        float v4 = lp[4], v5 = lp[5], v6 = lp[6], v7 = lp[7], v8 = lp[8];
        float* mp = m + (size_t)(node0 + r) * 12;
        float4 w0; w0.x = v0; w0.y = v1; w0.z = v2; w0.w = v3;
        float4 w1; w1.x = v4; w1.y = v5; w1.z = v6; w1.w = v7;
        ((float4*)mp)[0] = w0;
        ((float4*)mp)[1] = w1;
        mp[8] = v8;
    }
}

// ---------------- node round: fx MLP + next p/base1 ----------------

__global__ __launch_bounds__(512) void node7_k(
    const float* __restrict__ Xin, const float* __restrict__ m,
    const float* __restrict__ fxW1, const float* __restrict__ fxb1,
    const float* __restrict__ fxW2, const float* __restrict__ fxb2,
    const float* __restrict__ fxW3, const float* __restrict__ fxb3,
    const float* __restrict__ feW1, const float* __restrict__ feb1,
    float* __restrict__ Xout, float* __restrict__ p, float* __restrict__ base1)
{
    __shared__ float sU1[225], sU2[81], sU3[144];
    __shared__ float sWd[144], sWs[144];
    __shared__ float snb[34], sb1[9];
    const int t = threadIdx.x;
    if (t < 225) sU1[t] = fxW1[t];
    if (t < 81)  sU2[t] = fxW2[t];
    if (t < 144) { sU3[t] = fxW3[t]; sWd[t] = feW1[t]; sWs[t] = feW1[144 + t]; }
    if (t < 9) { snb[t] = fxb1[t]; snb[9 + t] = fxb2[t]; sb1[t] = feb1[t]; }
    if (t >= 32 && t < 48) snb[18 + (t - 32)] = fxb3[t - 32];
    __syncthreads();

    const int n = blockIdx.x * 512 + t;
    if (n >= NN) return;

    float xr[16];
    const float4* q = reinterpret_cast<const float4*>(Xin + (size_t)n * 16);
    #pragma unroll
    for (int k = 0; k < 4; ++k) {
        float4 v = q[k];
        xr[4*k] = v.x; xr[4*k+1] = v.y; xr[4*k+2] = v.z; xr[4*k+3] = v.w;
    }
    float mm[9];
    const float* mp = m + (size_t)n * 12;
    {
        float4 a = *(const float4*)mp;
        float4 b = *(const float4*)(mp + 4);
        mm[0] = a.x; mm[1] = a.y; mm[2] = a.z; mm[3] = a.w;
        mm[4] = b.x; mm[5] = b.y; mm[6] = b.z; mm[7] = b.w;
        mm[8] = mp[8];
    }

    float h1[9];
    #pragma unroll
    for (int j = 0; j < 9; ++j) h1[j] = snb[j];
    #pragma unroll
    for (int i = 0; i < 16; ++i) {
        const float xi = xr[i];
        #pragma unroll
        for (int j = 0; j < 9; ++j) h1[j] = fmaf(xi, sU1[i * 9 + j], h1[j]);
    }
    #pragma unroll
    for (int i = 0; i < 9; ++i) {
        const float xi = mm[i];
        #pragma unroll
        for (int j = 0; j < 9; ++j) h1[j] = fmaf(xi, sU1[(16 + i) * 9 + j], h1[j]);
    }
    #pragma unroll
    for (int j = 0; j < 9; ++j) h1[j] = fmaxf(h1[j], 0.f);

    float h2[9];
    #pragma unroll
    for (int j = 0; j < 9; ++j) h2[j] = snb[9 + j];
    #pragma unroll
    for (int i = 0; i < 9; ++i) {
        const float xi = h1[i];
        #pragma unroll
        for (int j = 0; j < 9; ++j) h2[j] = fmaf(xi, sU2[i * 9 + j], h2[j]);
    }
    #pragma unroll
    for (int j = 0; j < 9; ++j) h2[j] = fmaxf(h2[j], 0.f);

    float o[16];
    #pragma unroll
    for (int k = 0; k < 16; ++k) o[k] = snb[18 + k];
    #pragma unroll
    for (int j = 0; j < 9; ++j) {
        const float hj = h2[j];
        #pragma unroll
        for (int k = 0; k < 16; ++k) o[k] = fmaf(hj, sU3[j * 16 + k], o[k]);
    }

    float4* po = reinterpret_cast<float4*>(Xout + (size_t)n * 16);
    #pragma unroll
    for (int k = 0; k < 4; ++k) {
        float4 v;
        v.x = o[4*k]; v.y = o[4*k+1]; v.z = o[4*k+2]; v.w = o[4*k+3];
        po[k] = v;
    }

    float a[9], b[9];
    #pragma unroll
    for (int j = 0; j < 9; ++j) { a[j] = 0.f; b[j] = sb1[j]; }
    #pragma unroll
    for (int i = 0; i < 16; ++i) {
        const float xi = o[i];
        #pragma unroll
        for (int j = 0; j < 9; ++j) {
            a[j] = fmaf(xi, sWs[i * 9 + j], a[j]);
            b[j] = fmaf(xi, sWd[i * 9 + j], b[j]);
        }
    }
    float* pp = p + (size_t)n * 9;
    float* bp = base1 + (size_t)n * 9;
    #pragma unroll
    for (int j = 0; j < 9; ++j) { pp[j] = a[j]; bp[j] = b[j]; }
}

extern "C" void kernel_launch(void* const* d_in, const int* in_sizes, int n_in,
                              void* d_out, int out_size, void* d_ws, size_t ws_size,
                              hipStream_t stream)
{
    const float* X0   = (const float*)d_in[0];
    const int*   esrc = (const int*)d_in[1];
    const int*   edst = (const int*)d_in[2];
    const float* feW1 = (const float*)d_in[3];
    const float* feb1 = (const float*)d_in[4];
    const float* feW2 = (const float*)d_in[5];
    const float* feb2 = (const float*)d_in[6];
    const float* feW3 = (const float*)d_in[7];
    const float* feb3 = (const float*)d_in[8];
    const float* fxW1 = (const float*)d_in[9];
    const float* fxb1 = (const float*)d_in[10];
    const float* fxW2 = (const float*)d_in[11];
    const float* fxb2 = (const float*)d_in[12];
    const float* fxW3 = (const float*)d_in[13];
    const float* fxb3 = (const float*)d_in[14];
    float* out = (float*)d_out;

    // workspace (4B units)
    unsigned* sed = (unsigned*)d_ws;                            // NE u32
    float* Xa    = (float*)(sed + NE);                          // NN*16
    float* Xb    = Xa + (size_t)NN * 16;                        // NN*16
    float* p     = Xb + (size_t)NN * 16;                        // NN*9 (tight)
    float* base1 = p + (size_t)NN * 9;                          // NN*9 (tight)
    float* mb    = base1 + (size_t)NN * 9;                      // NN*12
    int* gcnt    = (int*)(mb + (size_t)NN * 12);                // NB (+pad)
    int* bstart  = gcnt + (NB + 2);                             // NB+1 (+pad)
    int* bbase   = bstart + (NB + 2);                           // NBLD*NB

    const dim3 gB(NBLD), tB(256);
    const dim3 gN((NN + 511) / 512), tN(512);
    const dim3 gR(NB), tR(256);

    // ---- build (once per launch) ----
    hipMemsetAsync(gcnt, 0, (size_t)NB * sizeof(int), stream);
    h1_k<<<gB, tB, 0, stream>>>(edst, gcnt, bbase);
    scan_k<<<1, 1024, 0, stream>>>(gcnt, bstart);
    s1_k<<<gB, tB, 0, stream>>>(esrc, edst, bstart, bbase, sed);

    // ---- rounds: X0 -> Xa -> Xb -> out ----
    init7_k<<<gN, tN, 0, stream>>>(X0, feW1, feb1, p, base1);

    round7_k<<<gR, tR, 0, stream>>>(sed, bstart, p, base1,
                                    feW2, feb2, feW3, feb3, mb);
    node7_k<<<gN, tN, 0, stream>>>(X0, mb, fxW1, fxb1, fxW2, fxb2, fxW3, fxb3,
                                   feW1, feb1, Xa, p, base1);

    round7_k<<<gR, tR, 0, stream>>>(sed, bstart, p, base1,
                                    feW2, feb2, feW3, feb3, mb);
    node7_k<<<gN, tN, 0, stream>>>(Xa, mb, fxW1, fxb1, fxW2, fxb2, fxW3, fxb3,
                                   feW1, feb1, Xb, p, base1);

    round7_k<<<gR, tR, 0, stream>>>(sed, bstart, p, base1,
                                    feW2, feb2, feW3, feb3, mb);
    node7_k<<<gN, tN, 0, stream>>>(Xb, mb, fxW1, fxb1, fxW2, fxb2, fxW3, fxb3,
                                   feW1, feb1, out, p, base1);
}